// Round 1
// baseline (462.912 us; speedup 1.0000x reference)
//
#include <hip/hip_runtime.h>
#include <math.h>

#define N_NODES 50000
#define N_EDGES 600000
#define F_INPUT 128
#define HCDIM 256
#define NGRAPH 64
#define NCLS 3
#define MPAD 50048   // 782 * 64, GEMM M padded
#define SCAN_NB ((N_NODES + 255) / 256)   // 196
#define LOG2E 1.4426950408889634f
#define NPART 32     // pooling partitions per graph
#define COLX_PAD 16  // zero padding entries after colx[total] (edge-loop prefetch reach)

// fused prep kernel block ranges
#define SPLITX_NB (MPAD * F_INPUT / 4 / 256)            // 6256
#define ZERO_NB   (((MPAD - N_NODES) * HCDIM / 4 + 255) / 256)  // 12
#define WPREP_NB  (512 * (F_INPUT + HCDIM + HCDIM) / 256)       // 1280
#define PREP_NB   (SPLITX_NB + ZERO_NB + WPREP_NB)
// fused hist+boundary ranges
#define HIST_NB   ((N_EDGES + N_NODES + 255) / 256)     // 2540
#define BND_NB    ((N_NODES + 255) / 256)               // 196

typedef float f32x4 __attribute__((ext_vector_type(4)));
typedef float f32x2 __attribute__((ext_vector_type(2)));
typedef _Float16 f16x8 __attribute__((ext_vector_type(8)));
typedef _Float16 f16x4 __attribute__((ext_vector_type(4)));
typedef _Float16 h2 __attribute__((ext_vector_type(2)));

__device__ __forceinline__ void gl_lds16(const void* g, void* l) {
    __builtin_amdgcn_global_load_lds(
        (const __attribute__((address_space(1))) unsigned int*)g,
        (__attribute__((address_space(3))) unsigned int*)l, 16, 0, 0);
}

__device__ __forceinline__ h2 bch2(unsigned int u) { return __builtin_bit_cast(h2, u); }
__device__ __forceinline__ h2 pk16(float a, float b) {
    return __builtin_bit_cast(h2, __builtin_amdgcn_cvt_pkrtz(a, b));
}

// ============================ hist + boundary (fused) ============================
__global__ void hist_boundary_kernel(const int* __restrict__ ei, int* __restrict__ deg,
                                     const int* __restrict__ batch,
                                     int* __restrict__ startg, int* __restrict__ endg) {
    int b = blockIdx.x;
    if (b < HIST_NB) {
        int i = b * 256 + threadIdx.x;
        int total = N_EDGES + N_NODES;
        if (i >= total) return;
        int d = (i < N_EDGES) ? ei[N_EDGES + i] : (i - N_EDGES);
        atomicAdd(&deg[d], 1);
    } else {
        int i = (b - HIST_NB) * 256 + threadIdx.x;
        if (i >= N_NODES) return;
        int g = batch[i];
        if (i == 0 || batch[i - 1] != g) startg[g] = i;
        if (i == N_NODES - 1 || batch[i + 1] != g) endg[g] = i + 1;
    }
}

// ============================ CSR scan ============================
__global__ void block_scan_kernel(const int* __restrict__ deg, int* __restrict__ rowptr,
                                  int* __restrict__ bsums) {
    __shared__ int wt[4];
    int b = blockIdx.x, t = threadIdx.x, lane = t & 63, wid = t >> 6;
    int i = b * 256 + t;
    int v = (i < N_NODES) ? deg[i] : 0;
    int x = v;
    #pragma unroll
    for (int off = 1; off < 64; off <<= 1) {
        int y = __shfl_up(x, off, 64);
        if (lane >= off) x += y;
    }
    if (lane == 63) wt[wid] = x;
    __syncthreads();
    if (t == 0) {
        int s = 0;
        #pragma unroll
        for (int j = 0; j < 4; ++j) { int tv = wt[j]; wt[j] = s; s += tv; }
        bsums[b] = s;
    }
    __syncthreads();
    if (i < N_NODES) rowptr[i] = wt[wid] + x - v;
}

// add_off with in-block bsums prefix (replaces the separate 1-block scan kernel)
__global__ void add_off_kernel(int* __restrict__ rowptr, int* __restrict__ cursor,
                               const int* __restrict__ bsums) {
    __shared__ int red[256];
    int b = blockIdx.x, t = threadIdx.x;
    red[t] = (t < b) ? bsums[t] : 0;   // b <= SCAN_NB-1 < 256
    __syncthreads();
    for (int off = 128; off > 0; off >>= 1) {
        if (t < off) red[t] += red[t + off];
        __syncthreads();
    }
    int offv = red[0];
    int i = b * 256 + t;
    if (i < N_NODES) {
        int r = rowptr[i] + offv;
        rowptr[i] = r;
        cursor[i] = r;
    }
    if (i == 0) rowptr[N_NODES] = N_EDGES + N_NODES;
}

// colx stores BYTE offsets into the fp8 xl matrix: s * HCDIM (256 B rows).
// Entries [total, total+COLX_PAD) are zero padding so the edge loop's deeper
// prefetch pipeline (up to e+20+q ahead) needs no clamps.
__global__ void fill_kernel(const int* __restrict__ ei, int* __restrict__ cursor,
                            int* __restrict__ colx) {
    int i = blockIdx.x * 256 + threadIdx.x;
    int total = N_EDGES + N_NODES;
    if (i >= total + COLX_PAD) return;
    if (i >= total) { colx[i] = 0; return; }
    int s, d;
    if (i < N_EDGES) { s = ei[i]; d = ei[N_EDGES + i]; }
    else             { s = i - N_EDGES; d = s; }
    int pos = atomicAdd(&cursor[d], 1);
    colx[pos] = s * HCDIM;
}

// ============================ Fused prep: x->fp16, pad zero, W->fp16 n-major ============================
__global__ void prep_kernel(const float* __restrict__ x, _Float16* __restrict__ A,
                            _Float16* __restrict__ Bt0, _Float16* __restrict__ Bt1,
                            _Float16* __restrict__ Bt2,
                            const float* __restrict__ Wl0, const float* __restrict__ Wr0,
                            const float* __restrict__ Wl1, const float* __restrict__ Wr1,
                            const float* __restrict__ Wl2, const float* __restrict__ Wr2) {
    int b = blockIdx.x;
    if (b < SPLITX_NB) {
        int base = (b * 256 + threadIdx.x) * 4;
        int row = base >> 7;
        float4 v = make_float4(0.f, 0.f, 0.f, 0.f);
        if (row < N_NODES) v = *(const float4*)&x[base];
        f16x4 o;
        o.x = (_Float16)v.x; o.y = (_Float16)v.y; o.z = (_Float16)v.z; o.w = (_Float16)v.w;
        *(f16x4*)&A[base] = o;
    } else if (b < SPLITX_NB + ZERO_NB) {
        int i = ((b - SPLITX_NB) * 256 + threadIdx.x) * 4;
        if (i < (MPAD - N_NODES) * HCDIM) {
            f16x4 z = {(_Float16)0.f, (_Float16)0.f, (_Float16)0.f, (_Float16)0.f};
            *(f16x4*)&A[(size_t)N_NODES * HCDIM + i] = z;
        }
    } else {
        int t = (b - SPLITX_NB - ZERO_NB) * 256 + threadIdx.x;
        const float* Wl; const float* Wr; _Float16* Bt; int K;
        if (t < 512 * F_INPUT)            { Wl = Wl0; Wr = Wr0; Bt = Bt0; K = F_INPUT; }
        else if (t < 512 * (F_INPUT + HCDIM)) { t -= 512 * F_INPUT; Wl = Wl1; Wr = Wr1; Bt = Bt1; K = HCDIM; }
        else                              { t -= 512 * (F_INPUT + HCDIM); Wl = Wl2; Wr = Wr2; Bt = Bt2; K = HCDIM; }
        int n = t & 511, k = t >> 9;
        float w = (n < 256) ? Wl[k * 256 + n] : Wr[k * 256 + (n - 256)];
        Bt[n * K + k] = (_Float16)w;
    }
}

// ============================ fp16 MFMA GEMM, 64x128 tile, BK=64 ============================
__global__ __launch_bounds__(256) void gemm_mfma(
    const _Float16* __restrict__ A, const _Float16* __restrict__ B,
    int K,
    const float* __restrict__ bl, const float* __restrict__ br,
    unsigned char* __restrict__ xl8, _Float16* __restrict__ xrh)
{
    __shared__ _Float16 sA[64 * 64], sB[128 * 64];
    int tid = threadIdx.x;
    int lane = tid & 63, wave = tid >> 6;
    int wm = wave >> 1, wn = wave & 1;
    int bx = blockIdx.x >> 2, by = blockIdx.x & 3;
    int row0 = bx * 64;
    int n0 = by * 128;
    int quad = lane >> 4, l16 = lane & 15;

    f32x4 acc[2][4];
    #pragma unroll
    for (int i = 0; i < 2; ++i)
        #pragma unroll
        for (int j = 0; j < 4; ++j)
            acc[i][j] = (f32x4){0.f, 0.f, 0.f, 0.f};

    for (int k0 = 0; k0 < K; k0 += 64) {
        __syncthreads();
        #pragma unroll
        for (int pass = 0; pass < 2; ++pass) {
            int c = tid + pass * 256;           // A chunk 0..511
            int r = c >> 3;
            int pl = c & 7;
            int pg = pl ^ (r & 7);
            size_t ga = (size_t)(row0 + r) * K + k0 + pg * 8;
            gl_lds16(A + ga, sA + c * 8);
        }
        #pragma unroll
        for (int pass = 0; pass < 4; ++pass) {
            int c = tid + pass * 256;           // B chunk 0..1023
            int r = c >> 3;
            int pl = c & 7;
            int pg = pl ^ (r & 7);
            size_t gb = (size_t)(n0 + r) * K + k0 + pg * 8;
            gl_lds16(B + gb, sB + c * 8);
        }
        __syncthreads();

        #pragma unroll
        for (int kk = 0; kk < 2; ++kk) {
            f16x8 fa[2], fb[4];
            #pragma unroll
            for (int i = 0; i < 2; ++i) {
                int rr = wm * 32 + i * 16 + l16;
                int ca = (kk * 4 + quad) ^ (rr & 7);
                fa[i] = *(const f16x8*)&sA[rr * 64 + ca * 8];
            }
            #pragma unroll
            for (int j = 0; j < 4; ++j) {
                int nn = wn * 64 + j * 16 + l16;
                int cb = (kk * 4 + quad) ^ (nn & 7);
                fb[j] = *(const f16x8*)&sB[nn * 64 + cb * 8];
            }
            #pragma unroll
            for (int i = 0; i < 2; ++i)
                #pragma unroll
                for (int j = 0; j < 4; ++j)
                    acc[i][j] = __builtin_amdgcn_mfma_f32_16x16x32_f16(fa[i], fb[j], acc[i][j], 0, 0, 0);
        }
    }

    if (by < 2) {
        int cb0 = by * 128;
        #pragma unroll
        for (int j = 0; j < 4; ++j) {
            int col = cb0 + wn * 64 + j * 16 + l16;
            float bj = bl[col];
            #pragma unroll
            for (int i = 0; i < 2; ++i) {
                int rbase = row0 + wm * 32 + i * 16 + quad * 4;
                #pragma unroll
                for (int r = 0; r < 4; ++r) {
                    int row = rbase + r;
                    if (row < N_NODES) {
                        float v = acc[i][j][r] + bj;
                        int pk = __builtin_amdgcn_cvt_pk_fp8_f32(v, v, 0, false);
                        xl8[(size_t)row * HCDIM + col] = (unsigned char)pk;
                    }
                }
            }
        }
    } else {
        int cb0 = (by - 2) * 128;
        #pragma unroll
        for (int j = 0; j < 4; ++j) {
            int col = cb0 + wn * 64 + j * 16 + l16;
            float bj = br[col];
            #pragma unroll
            for (int i = 0; i < 2; ++i) {
                int rbase = row0 + wm * 32 + i * 16 + quad * 4;
                #pragma unroll
                for (int r = 0; r < 4; ++r) {
                    int row = rbase + r;
                    if (row < N_NODES)
                        xrh[(size_t)row * HCDIM + col] = (_Float16)(acc[i][j][r] + bj);
                }
            }
        }
    }
}

// ============================ Edge phase: quarter-wave per edge, 2-group pipeline ============================
// 16 lanes per edge, 16 channels/lane. Lane (q=lane>>4, ql=lane&15): edge slot q,
// channels [ql*16, ql*16+16). 3-stage software pipeline: colx indices prefetched one
// iteration ahead of the gathers, gathers one iteration ahead of use, and TWO
// independent 4-edge groups per iteration (8 edges/iter) so two score/acc dependency
// chains are in flight. leaky_relu(0.2) as max(v, 0.2v) (pk_mul+pk_max). Accumulator
// kept as f32x2 pairs -> v_pk_fma_f32. colx padded +COLX_PAD(16) -> no prefetch clamps.
__global__ __launch_bounds__(256) void gat_edge(
    const unsigned char* __restrict__ xl8, const _Float16* __restrict__ xrh,
    const float* __restrict__ att, const float* __restrict__ bias,
    const int* __restrict__ rowptr, const int* __restrict__ colx,
    _Float16* __restrict__ outh, _Float16* __restrict__ onext, int mode)
{
    int wave = threadIdx.x >> 6;
    int lane = threadIdx.x & 63;
    int q  = lane >> 4;          // edge slot in group
    int ql = lane & 15;          // channel group: ch [ql*16, ql*16+16)
    int node = blockIdx.x * 4 + wave;
    if (node >= N_NODES) return;
    int cb = ql * 16;            // first channel / fp8 byte offset in row

    // xr channels cb..cb+15 (fp16, 32 B)
    const char* xrrow = (const char*)xrh + (size_t)node * (HCDIM * 2) + cb * 2;
    uint4 xu0 = *(const uint4*)xrrow;
    uint4 xu1 = *(const uint4*)(xrrow + 16);
    h2 xr[8] = { bch2(xu0.x), bch2(xu0.y), bch2(xu0.z), bch2(xu0.w),
                 bch2(xu1.x), bch2(xu1.y), bch2(xu1.z), bch2(xu1.w) };
    h2 at[8];
    #pragma unroll
    for (int i = 0; i < 8; ++i) {
        float2 av = *(const float2*)&att[cb + i * 2];
        at[i] = (h2){(_Float16)(av.x * LOG2E), (_Float16)(av.y * LOG2E)};
    }

    int e0 = rowptr[node], e1 = rowptr[node + 1];
    float denom = 0.f;
    f32x2 accp[8];               // accp[k] = channels {2k, 2k+1}
    #pragma unroll
    for (int i = 0; i < 8; ++i) accp[i] = (f32x2){0.f, 0.f};

    const unsigned char* xb = xl8 + cb;
    const h2 slope = {(_Float16)0.2f, (_Float16)0.2f};

    // pipeline prologue: stage-A (colx) + stage-B (gather) for groups 0,1;
    // stage-A for groups 2,3
    int cx0 = colx[e0 + q];
    int cx1 = colx[e0 + 4 + q];
    uint4 d0 = *(const uint4*)(xb + (unsigned)cx0);
    uint4 d1 = *(const uint4*)(xb + (unsigned)cx1);
    cx0 = colx[e0 + 8 + q];
    cx1 = colx[e0 + 12 + q];

    auto process = [&](uint4 dd, int ebase, bool masked) {
        unsigned int dw[4] = {dd.x, dd.y, dd.z, dd.w};
        f32x2 lo[4], hi[4];
        h2 hx[8];
        #pragma unroll
        for (int j = 0; j < 4; ++j) {
            lo[j] = __builtin_amdgcn_cvt_pk_f32_fp8(dw[j], false);
            hi[j] = __builtin_amdgcn_cvt_pk_f32_fp8(dw[j], true);
            hx[2 * j]     = pk16(lo[j].x, lo[j].y);
            hx[2 * j + 1] = pk16(hi[j].x, hi[j].y);
        }
        // score over own 16 channels (two 4-deep fdot2 chains)
        float pa = 0.f, pb = 0.f;
        #pragma unroll
        for (int i = 0; i < 4; ++i) {
            h2 va = hx[i] + xr[i];
            h2 vb = hx[i + 4] + xr[i + 4];
            va = __builtin_elementwise_max(va, va * slope);   // lrelu(0.2) = max(v, 0.2v)
            vb = __builtin_elementwise_max(vb, vb * slope);
            pa = __builtin_amdgcn_fdot2(va, at[i], pa, false);
            pb = __builtin_amdgcn_fdot2(vb, at[i + 4], pb, false);
        }
        float p = pa + pb;
        // head reduce: 4 lanes — xor1, xor2 via imm ds_swizzle
        p += __builtin_bit_cast(float, __builtin_amdgcn_ds_swizzle(__builtin_bit_cast(int, p), 0x041F));
        p += __builtin_bit_cast(float, __builtin_amdgcn_ds_swizzle(__builtin_bit_cast(int, p), 0x081F));
        float w = exp2f(p);
        if (masked) w = (ebase + q < e1) ? w : 0.f;
        denom += w;
        f32x2 wp = {w, w};
        #pragma unroll
        for (int j = 0; j < 4; ++j) {
            accp[2 * j]     += wp * lo[j];   // -> v_pk_fma_f32
            accp[2 * j + 1] += wp * hi[j];
        }
    };

    int e = e0;
    for (; e + 8 <= e1; e += 8) {
        uint4 n0 = *(const uint4*)(xb + (unsigned)cx0);   // stage-B groups k+2,k+3
        uint4 n1 = *(const uint4*)(xb + (unsigned)cx1);
        cx0 = colx[e + 16 + q];                           // stage-A groups k+4,k+5
        cx1 = colx[e + 20 + q];
        process(d0, e, false);
        process(d1, e + 4, false);
        d0 = n0; d1 = n1;
    }
    // tail: 0..2 masked groups; their gathers are already in flight (d0/d1)
    if (e < e1) {
        process(d0, e, true);
        e += 4;
        if (e < e1) process(d1, e, true);
    }

    // cross-quarter reduce (edges were split over the 4 quarters; ql/head invariant)
    denom += __shfl_xor(denom, 16, 64);
    denom += __shfl_xor(denom, 32, 64);
    #pragma unroll
    for (int i = 0; i < 8; ++i) {
        accp[i].x += __shfl_xor(accp[i].x, 16, 64);
        accp[i].x += __shfl_xor(accp[i].x, 32, 64);
        accp[i].y += __shfl_xor(accp[i].y, 16, 64);
        accp[i].y += __shfl_xor(accp[i].y, 32, 64);
    }

    if (q == 0) {
        float inv = 1.f / denom;
        char* orow = (char*)(mode == 0 ? outh : onext) + (size_t)node * (HCDIM * 2) + cb * 2;
        h2 o[8];
        #pragma unroll
        for (int i = 0; i < 8; ++i) {
            float2 bv = *(const float2*)&bias[cb + i * 2];
            float v0 = accp[i].x * inv + bv.x;
            float v1 = accp[i].y * inv + bv.y;
            if (mode != 0) { v0 = fmaxf(v0, 0.f); v1 = fmaxf(v1, 0.f); }
            o[i] = pk16(v0, v1);
        }
        uint4 s0 = { __builtin_bit_cast(unsigned int, o[0]), __builtin_bit_cast(unsigned int, o[1]),
                     __builtin_bit_cast(unsigned int, o[2]), __builtin_bit_cast(unsigned int, o[3]) };
        uint4 s1 = { __builtin_bit_cast(unsigned int, o[4]), __builtin_bit_cast(unsigned int, o[5]),
                     __builtin_bit_cast(unsigned int, o[6]), __builtin_bit_cast(unsigned int, o[7]) };
        *(uint4*)orow = s0;
        *(uint4*)(orow + 16) = s1;
    }
}

// ============================ Two-stage pooling ============================
__global__ __launch_bounds__(256) void pool_partial(
    const _Float16* __restrict__ h, const int* __restrict__ startg,
    const int* __restrict__ endg, float* __restrict__ sumP, float* __restrict__ maxP)
{
    __shared__ float4 sS[4][64];
    __shared__ float4 sM[4][64];
    int g = blockIdx.x >> 5, part = blockIdx.x & (NPART - 1);
    int lane = threadIdx.x & 63;
    int sub = threadIdx.x >> 6;
    int c0 = lane * 4;
    int s = startg[g], e = endg[g];
    float4 sum = make_float4(0.f, 0.f, 0.f, 0.f);
    float4 mx = make_float4(-INFINITY, -INFINITY, -INFINITY, -INFINITY);
    for (int i = s + part * 4 + sub; i < e; i += NPART * 4) {
        uint2 u = *(const uint2*)&h[(size_t)i * HCDIM + c0];
        h2 a = bch2(u.x), b = bch2(u.y);
        float4 v = make_float4((float)a.x, (float)a.y, (float)b.x, (float)b.y);
        sum.x += v.x; sum.y += v.y; sum.z += v.z; sum.w += v.w;
        mx.x = fmaxf(mx.x, v.x); mx.y = fmaxf(mx.y, v.y);
        mx.z = fmaxf(mx.z, v.z); mx.w = fmaxf(mx.w, v.w);
    }
    sS[sub][lane] = sum; sM[sub][lane] = mx;
    __syncthreads();
    if (sub == 0) {
        #pragma unroll
        for (int j = 1; j < 4; ++j) {
            float4 a = sS[j][lane], b = sM[j][lane];
            sum.x += a.x; sum.y += a.y; sum.z += a.z; sum.w += a.w;
            mx.x = fmaxf(mx.x, b.x); mx.y = fmaxf(mx.y, b.y);
            mx.z = fmaxf(mx.z, b.z); mx.w = fmaxf(mx.w, b.w);
        }
        size_t o = (size_t)blockIdx.x * HCDIM + c0;
        *(float4*)&sumP[o] = sum;
        *(float4*)&maxP[o] = mx;
    }
}

// Stage 2 + logits + softmax fused
__global__ __launch_bounds__(256) void pool_final_logits(
    const float* __restrict__ sumP, const float* __restrict__ maxP,
    const int* __restrict__ startg, const int* __restrict__ endg,
    const float* __restrict__ Wout, const float* __restrict__ bout,
    float* __restrict__ out)
{
    __shared__ float red[256];
    __shared__ float lg[NCLS];
    int g = blockIdx.x, c = threadIdx.x;
    float s = 0.f, m = -INFINITY;
    #pragma unroll 8
    for (int part = 0; part < NPART; ++part) {
        size_t o = (size_t)(g * NPART + part) * HCDIM + c;
        s += sumP[o];
        m = fmaxf(m, maxP[o]);
    }
    int cnt = endg[g] - startg[g];
    float inv = 1.f / fmaxf((float)cnt, 1.f);
    float pv = s * inv + m;

    for (int j = 0; j < NCLS; ++j) {
        red[c] = pv * Wout[c * NCLS + j];
        __syncthreads();
        for (int off = 128; off > 0; off >>= 1) {
            if (c < off) red[c] += red[c + off];
            __syncthreads();
        }
        if (c == 0) lg[j] = red[0] + bout[j];
        __syncthreads();
    }
    if (c == 0) {
        float mx = fmaxf(lg[0], fmaxf(lg[1], lg[2]));
        float e0 = __expf(lg[0] - mx), e1 = __expf(lg[1] - mx), e2 = __expf(lg[2] - mx);
        float invs = 1.f / (e0 + e1 + e2);
        out[g * NCLS + 0] = e0 * invs;
        out[g * NCLS + 1] = e1 * invs;
        out[g * NCLS + 2] = e2 * invs;
    }
}

// ============================ Orchestration ============================
extern "C" void kernel_launch(void* const* d_in, const int* in_sizes, int n_in,
                              void* d_out, int out_size, void* d_ws, size_t ws_size,
                              hipStream_t stream) {
    const float* x     = (const float*)d_in[0];
    const int*   ei    = (const int*)d_in[1];
    const int*   batch = (const int*)d_in[2];
    const float *Wl[3], *bl[3], *Wr[3], *br[3], *att[3], *bias[3];
    for (int li = 0; li < 3; ++li) {
        int b = 3 + li * 6;
        Wl[li]   = (const float*)d_in[b + 0];
        bl[li]   = (const float*)d_in[b + 1];
        Wr[li]   = (const float*)d_in[b + 2];
        br[li]   = (const float*)d_in[b + 3];
        att[li]  = (const float*)d_in[b + 4];
        bias[li] = (const float*)d_in[b + 5];
    }
    const float* Wout = (const float*)d_in[21];
    const float* bout = (const float*)d_in[22];
    float* out = (float*)d_out;

    size_t off = 0;
    char* wsb = (char*)d_ws;
    auto alloc = [&](size_t bytes) -> char* {
        char* ptr = wsb + off;
        off += (bytes + 255) & ~(size_t)255;
        return ptr;
    };
    int* zblk    = (int*)alloc((N_NODES + 2 * NGRAPH) * sizeof(int));
    int* deg     = zblk;
    int* startg  = zblk + N_NODES;
    int* endg    = zblk + N_NODES + NGRAPH;
    int* rowptr  = (int*)alloc((N_NODES + 1) * sizeof(int));
    int* cursor  = (int*)alloc(N_NODES * sizeof(int));
    int* bsums   = (int*)alloc(256 * sizeof(int));
    int* colx    = (int*)alloc((size_t)(N_EDGES + N_NODES + COLX_PAD) * sizeof(int));
    _Float16* Abuf = (_Float16*)alloc((size_t)MPAD * HCDIM * sizeof(_Float16));
    _Float16* Bt[3];
    for (int li = 0; li < 3; ++li) {
        int K = (li == 0) ? F_INPUT : HCDIM;
        Bt[li] = (_Float16*)alloc((size_t)512 * K * sizeof(_Float16));
    }
    unsigned char* xl8 = (unsigned char*)alloc((size_t)N_NODES * HCDIM);
    _Float16* xrh  = (_Float16*)alloc((size_t)N_NODES * HCDIM * sizeof(_Float16));
    _Float16* hbuf = (_Float16*)alloc((size_t)N_NODES * HCDIM * sizeof(_Float16));
    float* sumP    = (float*)alloc((size_t)NGRAPH * NPART * HCDIM * sizeof(float));
    float* maxP    = (float*)alloc((size_t)NGRAPH * NPART * HCDIM * sizeof(float));

    hipMemsetAsync(zblk, 0, (N_NODES + 2 * NGRAPH) * sizeof(int), stream);

    hist_boundary_kernel<<<HIST_NB + BND_NB, 256, 0, stream>>>(ei, deg, batch, startg, endg);
    block_scan_kernel<<<SCAN_NB, 256, 0, stream>>>(deg, rowptr, bsums);
    add_off_kernel<<<SCAN_NB, 256, 0, stream>>>(rowptr, cursor, bsums);
    fill_kernel<<<(N_EDGES + N_NODES + COLX_PAD + 255) / 256, 256, 0, stream>>>(ei, cursor, colx);

    prep_kernel<<<PREP_NB, 256, 0, stream>>>(x, Abuf, Bt[0], Bt[1], Bt[2],
                                             Wl[0], Wr[0], Wl[1], Wr[1], Wl[2], Wr[2]);

    for (int li = 0; li < 3; ++li) {
        int K = (li == 0) ? F_INPUT : HCDIM;
        gemm_mfma<<<(MPAD / 64) * 4, 256, 0, stream>>>(
            Abuf, Bt[li], K, bl[li], br[li], xl8, xrh);
        if (li < 2) {
            gat_edge<<<N_NODES / 4, 256, 0, stream>>>(
                xl8, xrh, att[li], bias[li], rowptr, colx, nullptr, Abuf, 1);
        } else {
            gat_edge<<<N_NODES / 4, 256, 0, stream>>>(
                xl8, xrh, att[li], bias[li], rowptr, colx, hbuf, nullptr, 0);
        }
    }

    pool_partial<<<NGRAPH * NPART, 256, 0, stream>>>(hbuf, startg, endg, sumP, maxP);
    pool_final_logits<<<NGRAPH, 256, 0, stream>>>(sumP, maxP, startg, endg, Wout, bout, out);
}

// Round 2
// 461.262 us; speedup vs baseline: 1.0036x; 1.0036x over previous
//
#include <hip/hip_runtime.h>
#include <math.h>

#define N_NODES 50000
#define N_EDGES 600000
#define F_INPUT 128
#define HCDIM 256
#define NGRAPH 64
#define NCLS 3
#define MPAD 50048   // 782 * 64, GEMM M padded
#define SCAN_NB ((N_NODES + 255) / 256)   // 196
#define LOG2E 1.4426950408889634f
#define NPART 32     // pooling partitions per graph
#define COLX_PAD 16  // zero padding entries after colx[total]
#define TOTAL_E (N_EDGES + N_NODES)

// fused prep kernel block ranges
#define SPLITX_NB (MPAD * F_INPUT / 4 / 256)            // 6256
#define ZERO_NB   (((MPAD - N_NODES) * HCDIM / 4 + 255) / 256)  // 12
#define WPREP_NB  (512 * (F_INPUT + HCDIM + HCDIM) / 256)       // 1280
#define PREP_NB   (SPLITX_NB + ZERO_NB + WPREP_NB)
// fused hist+boundary ranges
#define HIST_NB   ((N_EDGES + N_NODES + 255) / 256)     // 2540
#define BND_NB    ((N_NODES + 255) / 256)               // 196

typedef float f32x4 __attribute__((ext_vector_type(4)));
typedef float f32x2 __attribute__((ext_vector_type(2)));
typedef _Float16 f16x8 __attribute__((ext_vector_type(8)));
typedef _Float16 f16x4 __attribute__((ext_vector_type(4)));
typedef _Float16 h2 __attribute__((ext_vector_type(2)));

__device__ __forceinline__ void gl_lds16(const void* g, void* l) {
    __builtin_amdgcn_global_load_lds(
        (const __attribute__((address_space(1))) unsigned int*)g,
        (__attribute__((address_space(3))) unsigned int*)l, 16, 0, 0);
}

__device__ __forceinline__ h2 bch2(unsigned int u) { return __builtin_bit_cast(h2, u); }
__device__ __forceinline__ h2 pk16(float a, float b) {
    return __builtin_bit_cast(h2, __builtin_amdgcn_cvt_pkrtz(a, b));
}

// ============================ hist + boundary (fused) ============================
__global__ void hist_boundary_kernel(const int* __restrict__ ei, int* __restrict__ deg,
                                     const int* __restrict__ batch,
                                     int* __restrict__ startg, int* __restrict__ endg) {
    int b = blockIdx.x;
    if (b < HIST_NB) {
        int i = b * 256 + threadIdx.x;
        int total = N_EDGES + N_NODES;
        if (i >= total) return;
        int d = (i < N_EDGES) ? ei[N_EDGES + i] : (i - N_EDGES);
        atomicAdd(&deg[d], 1);
    } else {
        int i = (b - HIST_NB) * 256 + threadIdx.x;
        if (i >= N_NODES) return;
        int g = batch[i];
        if (i == 0 || batch[i - 1] != g) startg[g] = i;
        if (i == N_NODES - 1 || batch[i + 1] != g) endg[g] = i + 1;
    }
}

// ============================ CSR scan ============================
__global__ void block_scan_kernel(const int* __restrict__ deg, int* __restrict__ rowptr,
                                  int* __restrict__ bsums) {
    __shared__ int wt[4];
    int b = blockIdx.x, t = threadIdx.x, lane = t & 63, wid = t >> 6;
    int i = b * 256 + t;
    int v = (i < N_NODES) ? deg[i] : 0;
    int x = v;
    #pragma unroll
    for (int off = 1; off < 64; off <<= 1) {
        int y = __shfl_up(x, off, 64);
        if (lane >= off) x += y;
    }
    if (lane == 63) wt[wid] = x;
    __syncthreads();
    if (t == 0) {
        int s = 0;
        #pragma unroll
        for (int j = 0; j < 4; ++j) { int tv = wt[j]; wt[j] = s; s += tv; }
        bsums[b] = s;
    }
    __syncthreads();
    if (i < N_NODES) rowptr[i] = wt[wid] + x - v;
}

// add_off with in-block bsums prefix
__global__ void add_off_kernel(int* __restrict__ rowptr, int* __restrict__ cursor,
                               const int* __restrict__ bsums) {
    __shared__ int red[256];
    int b = blockIdx.x, t = threadIdx.x;
    red[t] = (t < b) ? bsums[t] : 0;   // b <= SCAN_NB-1 < 256
    __syncthreads();
    for (int off = 128; off > 0; off >>= 1) {
        if (t < off) red[t] += red[t + off];
        __syncthreads();
    }
    int offv = red[0];
    int i = b * 256 + t;
    if (i < N_NODES) {
        int r = rowptr[i] + offv;
        rowptr[i] = r;
        cursor[i] = r;
    }
    if (i == 0) rowptr[N_NODES] = N_EDGES + N_NODES;
}

// colx stores BYTE offsets into the fp8 xl matrix: s * HCDIM (256 B rows).
// Entries [total, total+COLX_PAD) are zero padding; in-loop prefetch indices are
// clamped to TOTAL_E so any overrun reads padding (row 0, masked out).
__global__ void fill_kernel(const int* __restrict__ ei, int* __restrict__ cursor,
                            int* __restrict__ colx) {
    int i = blockIdx.x * 256 + threadIdx.x;
    int total = N_EDGES + N_NODES;
    if (i >= total + COLX_PAD) return;
    if (i >= total) { colx[i] = 0; return; }
    int s, d;
    if (i < N_EDGES) { s = ei[i]; d = ei[N_EDGES + i]; }
    else             { s = i - N_EDGES; d = s; }
    int pos = atomicAdd(&cursor[d], 1);
    colx[pos] = s * HCDIM;
}

// ============================ Fused prep: x->fp16, pad zero, W->fp16 n-major ============================
__global__ void prep_kernel(const float* __restrict__ x, _Float16* __restrict__ A,
                            _Float16* __restrict__ Bt0, _Float16* __restrict__ Bt1,
                            _Float16* __restrict__ Bt2,
                            const float* __restrict__ Wl0, const float* __restrict__ Wr0,
                            const float* __restrict__ Wl1, const float* __restrict__ Wr1,
                            const float* __restrict__ Wl2, const float* __restrict__ Wr2) {
    int b = blockIdx.x;
    if (b < SPLITX_NB) {
        int base = (b * 256 + threadIdx.x) * 4;
        int row = base >> 7;
        float4 v = make_float4(0.f, 0.f, 0.f, 0.f);
        if (row < N_NODES) v = *(const float4*)&x[base];
        f16x4 o;
        o.x = (_Float16)v.x; o.y = (_Float16)v.y; o.z = (_Float16)v.z; o.w = (_Float16)v.w;
        *(f16x4*)&A[base] = o;
    } else if (b < SPLITX_NB + ZERO_NB) {
        int i = ((b - SPLITX_NB) * 256 + threadIdx.x) * 4;
        if (i < (MPAD - N_NODES) * HCDIM) {
            f16x4 z = {(_Float16)0.f, (_Float16)0.f, (_Float16)0.f, (_Float16)0.f};
            *(f16x4*)&A[(size_t)N_NODES * HCDIM + i] = z;
        }
    } else {
        int t = (b - SPLITX_NB - ZERO_NB) * 256 + threadIdx.x;
        const float* Wl; const float* Wr; _Float16* Bt; int K;
        if (t < 512 * F_INPUT)            { Wl = Wl0; Wr = Wr0; Bt = Bt0; K = F_INPUT; }
        else if (t < 512 * (F_INPUT + HCDIM)) { t -= 512 * F_INPUT; Wl = Wl1; Wr = Wr1; Bt = Bt1; K = HCDIM; }
        else                              { t -= 512 * (F_INPUT + HCDIM); Wl = Wl2; Wr = Wr2; Bt = Bt2; K = HCDIM; }
        int n = t & 511, k = t >> 9;
        float w = (n < 256) ? Wl[k * 256 + n] : Wr[k * 256 + (n - 256)];
        Bt[n * K + k] = (_Float16)w;
    }
}

// ============================ fp16 MFMA GEMM, 64x128 tile, BK=64 ============================
__global__ __launch_bounds__(256) void gemm_mfma(
    const _Float16* __restrict__ A, const _Float16* __restrict__ B,
    int K,
    const float* __restrict__ bl, const float* __restrict__ br,
    unsigned char* __restrict__ xl8, _Float16* __restrict__ xrh)
{
    __shared__ _Float16 sA[64 * 64], sB[128 * 64];
    int tid = threadIdx.x;
    int lane = tid & 63, wave = tid >> 6;
    int wm = wave >> 1, wn = wave & 1;
    int bx = blockIdx.x >> 2, by = blockIdx.x & 3;
    int row0 = bx * 64;
    int n0 = by * 128;
    int quad = lane >> 4, l16 = lane & 15;

    f32x4 acc[2][4];
    #pragma unroll
    for (int i = 0; i < 2; ++i)
        #pragma unroll
        for (int j = 0; j < 4; ++j)
            acc[i][j] = (f32x4){0.f, 0.f, 0.f, 0.f};

    for (int k0 = 0; k0 < K; k0 += 64) {
        __syncthreads();
        #pragma unroll
        for (int pass = 0; pass < 2; ++pass) {
            int c = tid + pass * 256;           // A chunk 0..511
            int r = c >> 3;
            int pl = c & 7;
            int pg = pl ^ (r & 7);
            size_t ga = (size_t)(row0 + r) * K + k0 + pg * 8;
            gl_lds16(A + ga, sA + c * 8);
        }
        #pragma unroll
        for (int pass = 0; pass < 4; ++pass) {
            int c = tid + pass * 256;           // B chunk 0..1023
            int r = c >> 3;
            int pl = c & 7;
            int pg = pl ^ (r & 7);
            size_t gb = (size_t)(n0 + r) * K + k0 + pg * 8;
            gl_lds16(B + gb, sB + c * 8);
        }
        __syncthreads();

        #pragma unroll
        for (int kk = 0; kk < 2; ++kk) {
            f16x8 fa[2], fb[4];
            #pragma unroll
            for (int i = 0; i < 2; ++i) {
                int rr = wm * 32 + i * 16 + l16;
                int ca = (kk * 4 + quad) ^ (rr & 7);
                fa[i] = *(const f16x8*)&sA[rr * 64 + ca * 8];
            }
            #pragma unroll
            for (int j = 0; j < 4; ++j) {
                int nn = wn * 64 + j * 16 + l16;
                int cb = (kk * 4 + quad) ^ (nn & 7);
                fb[j] = *(const f16x8*)&sB[nn * 64 + cb * 8];
            }
            #pragma unroll
            for (int i = 0; i < 2; ++i)
                #pragma unroll
                for (int j = 0; j < 4; ++j)
                    acc[i][j] = __builtin_amdgcn_mfma_f32_16x16x32_f16(fa[i], fb[j], acc[i][j], 0, 0, 0);
        }
    }

    if (by < 2) {
        int cb0 = by * 128;
        #pragma unroll
        for (int j = 0; j < 4; ++j) {
            int col = cb0 + wn * 64 + j * 16 + l16;
            float bj = bl[col];
            #pragma unroll
            for (int i = 0; i < 2; ++i) {
                int rbase = row0 + wm * 32 + i * 16 + quad * 4;
                #pragma unroll
                for (int r = 0; r < 4; ++r) {
                    int row = rbase + r;
                    if (row < N_NODES) {
                        float v = acc[i][j][r] + bj;
                        int pk = __builtin_amdgcn_cvt_pk_fp8_f32(v, v, 0, false);
                        xl8[(size_t)row * HCDIM + col] = (unsigned char)pk;
                    }
                }
            }
        }
    } else {
        int cb0 = (by - 2) * 128;
        #pragma unroll
        for (int j = 0; j < 4; ++j) {
            int col = cb0 + wn * 64 + j * 16 + l16;
            float bj = br[col];
            #pragma unroll
            for (int i = 0; i < 2; ++i) {
                int rbase = row0 + wm * 32 + i * 16 + quad * 4;
                #pragma unroll
                for (int r = 0; r < 4; ++r) {
                    int row = rbase + r;
                    if (row < N_NODES)
                        xrh[(size_t)row * HCDIM + col] = (_Float16)(acc[i][j][r] + bj);
                }
            }
        }
    }
}

// ============================ Edge phase: one node per 16-lane quarter ============================
// 16 nodes per block, 4 per wave (one per quarter). Lane (q=lane>>4, ql=lane&15):
// quarter q owns node base+q; lane covers channels [ql*16, ql*16+16) of that node.
// The 4 quarters' prologue chains (rowptr -> colx -> gather) run concurrently in one
// wave, and the edge loop runs max(deg over 4 nodes) iterations (deg ~13-18) — long
// enough for the gather-1-ahead / colx-3-ahead prefetch to reach steady state.
// Head softmax reduce = 2 imm ds_swizzle within 4-lane head groups (quarter-local).
// No cross-quarter reduce; denominator per (node, head) is lane-private. All 64 lanes
// store outputs (2 KB contiguous per wave). Overrun prefetch clamped to colx[TOTAL_E]=0.
__global__ __launch_bounds__(256) void gat_edge(
    const unsigned char* __restrict__ xl8, const _Float16* __restrict__ xrh,
    const float* __restrict__ att, const float* __restrict__ bias,
    const int* __restrict__ rowptr, const int* __restrict__ colx,
    _Float16* __restrict__ outh, _Float16* __restrict__ onext, int mode)
{
    int wave = threadIdx.x >> 6;
    int lane = threadIdx.x & 63;
    int q  = lane >> 4;          // node slot within wave
    int ql = lane & 15;          // channel group: ch [ql*16, ql*16+16)
    int node = (blockIdx.x * 4 + wave) * 4 + q;   // N_NODES = 16 * gridDim exactly
    int cb = ql * 16;            // first channel / fp8 byte offset in row

    int e0 = rowptr[node], e1 = rowptr[node + 1];
    int cnt = e1 - e0;
    // wave-uniform trip count = max over the 4 quarters
    int niter = cnt;
    niter = max(niter, __shfl_xor(niter, 16, 64));
    niter = max(niter, __shfl_xor(niter, 32, 64));

    // xr channels cb..cb+15 of own node (fp16, 32 B)
    const char* xrrow = (const char*)xrh + (size_t)node * (HCDIM * 2) + cb * 2;
    uint4 xu0 = *(const uint4*)xrrow;
    uint4 xu1 = *(const uint4*)(xrrow + 16);
    h2 xr[8] = { bch2(xu0.x), bch2(xu0.y), bch2(xu0.z), bch2(xu0.w),
                 bch2(xu1.x), bch2(xu1.y), bch2(xu1.z), bch2(xu1.w) };
    h2 at[8];
    #pragma unroll
    for (int i = 0; i < 8; ++i) {
        float2 av = *(const float2*)&att[cb + i * 2];
        at[i] = (h2){(_Float16)(av.x * LOG2E), (_Float16)(av.y * LOG2E)};
    }

    float denom = 0.f;
    f32x2 accp[8];               // accp[k] = channels {2k, 2k+1}
    #pragma unroll
    for (int i = 0; i < 8; ++i) accp[i] = (f32x2){0.f, 0.f};

    const unsigned char* xb = xl8 + cb;
    const h2 slope = {(_Float16)0.2f, (_Float16)0.2f};

    // pipeline prologue: colx for edges 0,1,2; gather edge 0
    int cx0 = colx[e0];                 // e0 < TOTAL_E always
    int cx1 = colx[e0 + 1];             // <= TOTAL_E (pad)
    int cx2 = colx[e0 + 2];             // <= TOTAL_E + 1 (pad)
    uint4 d0 = *(const uint4*)(xb + (unsigned)cx0);

    for (int i = 0; i < niter; ++i) {
        uint4 dn = *(const uint4*)(xb + (unsigned)cx1);   // gather edge i+1
        cx1 = cx2;
        unsigned nx = (unsigned)(e0 + i + 3);
        nx = nx < (unsigned)TOTAL_E ? nx : (unsigned)TOTAL_E;   // clamp into pad
        cx2 = colx[nx];                                   // colx edge i+3

        // ---- process edge e0+i from d0, masked by (i < cnt) ----
        unsigned int dw[4] = {d0.x, d0.y, d0.z, d0.w};
        f32x2 lo[4], hi[4];
        h2 hx[8];
        #pragma unroll
        for (int j = 0; j < 4; ++j) {
            lo[j] = __builtin_amdgcn_cvt_pk_f32_fp8(dw[j], false);
            hi[j] = __builtin_amdgcn_cvt_pk_f32_fp8(dw[j], true);
            hx[2 * j]     = pk16(lo[j].x, lo[j].y);
            hx[2 * j + 1] = pk16(hi[j].x, hi[j].y);
        }
        float pa = 0.f, pb = 0.f;
        #pragma unroll
        for (int j = 0; j < 4; ++j) {
            h2 va = hx[j] + xr[j];
            h2 vb = hx[j + 4] + xr[j + 4];
            va = __builtin_elementwise_max(va, va * slope);   // lrelu(0.2) = max(v, 0.2v)
            vb = __builtin_elementwise_max(vb, vb * slope);
            pa = __builtin_amdgcn_fdot2(va, at[j], pa, false);
            pb = __builtin_amdgcn_fdot2(vb, at[j + 4], pb, false);
        }
        float p = pa + pb;
        // head reduce within 4-lane groups (quarter-local): xor1, xor2
        p += __builtin_bit_cast(float, __builtin_amdgcn_ds_swizzle(__builtin_bit_cast(int, p), 0x041F));
        p += __builtin_bit_cast(float, __builtin_amdgcn_ds_swizzle(__builtin_bit_cast(int, p), 0x081F));
        float w = (i < cnt) ? exp2f(p) : 0.f;
        denom += w;
        f32x2 wp = {w, w};
        #pragma unroll
        for (int j = 0; j < 4; ++j) {
            accp[2 * j]     += wp * lo[j];   // -> v_pk_fma_f32
            accp[2 * j + 1] += wp * hi[j];
        }
        d0 = dn;
    }

    // epilogue: per-lane normalize + bias (+ relu), all 64 lanes store
    float inv = 1.f / denom;
    char* orow = (char*)(mode == 0 ? outh : onext) + (size_t)node * (HCDIM * 2) + cb * 2;
    h2 o[8];
    #pragma unroll
    for (int i = 0; i < 8; ++i) {
        float2 bv = *(const float2*)&bias[cb + i * 2];
        float v0 = accp[i].x * inv + bv.x;
        float v1 = accp[i].y * inv + bv.y;
        if (mode != 0) { v0 = fmaxf(v0, 0.f); v1 = fmaxf(v1, 0.f); }
        o[i] = pk16(v0, v1);
    }
    uint4 s0 = { __builtin_bit_cast(unsigned int, o[0]), __builtin_bit_cast(unsigned int, o[1]),
                 __builtin_bit_cast(unsigned int, o[2]), __builtin_bit_cast(unsigned int, o[3]) };
    uint4 s1 = { __builtin_bit_cast(unsigned int, o[4]), __builtin_bit_cast(unsigned int, o[5]),
                 __builtin_bit_cast(unsigned int, o[6]), __builtin_bit_cast(unsigned int, o[7]) };
    *(uint4*)orow = s0;
    *(uint4*)(orow + 16) = s1;
}

// ============================ Two-stage pooling ============================
__global__ __launch_bounds__(256) void pool_partial(
    const _Float16* __restrict__ h, const int* __restrict__ startg,
    const int* __restrict__ endg, float* __restrict__ sumP, float* __restrict__ maxP)
{
    __shared__ float4 sS[4][64];
    __shared__ float4 sM[4][64];
    int g = blockIdx.x >> 5, part = blockIdx.x & (NPART - 1);
    int lane = threadIdx.x & 63;
    int sub = threadIdx.x >> 6;
    int c0 = lane * 4;
    int s = startg[g], e = endg[g];
    float4 sum = make_float4(0.f, 0.f, 0.f, 0.f);
    float4 mx = make_float4(-INFINITY, -INFINITY, -INFINITY, -INFINITY);
    for (int i = s + part * 4 + sub; i < e; i += NPART * 4) {
        uint2 u = *(const uint2*)&h[(size_t)i * HCDIM + c0];
        h2 a = bch2(u.x), b = bch2(u.y);
        float4 v = make_float4((float)a.x, (float)a.y, (float)b.x, (float)b.y);
        sum.x += v.x; sum.y += v.y; sum.z += v.z; sum.w += v.w;
        mx.x = fmaxf(mx.x, v.x); mx.y = fmaxf(mx.y, v.y);
        mx.z = fmaxf(mx.z, v.z); mx.w = fmaxf(mx.w, v.w);
    }
    sS[sub][lane] = sum; sM[sub][lane] = mx;
    __syncthreads();
    if (sub == 0) {
        #pragma unroll
        for (int j = 1; j < 4; ++j) {
            float4 a = sS[j][lane], b = sM[j][lane];
            sum.x += a.x; sum.y += a.y; sum.z += a.z; sum.w += a.w;
            mx.x = fmaxf(mx.x, b.x); mx.y = fmaxf(mx.y, b.y);
            mx.z = fmaxf(mx.z, b.z); mx.w = fmaxf(mx.w, b.w);
        }
        size_t o = (size_t)blockIdx.x * HCDIM + c0;
        *(float4*)&sumP[o] = sum;
        *(float4*)&maxP[o] = mx;
    }
}

// Stage 2 + logits + softmax fused
__global__ __launch_bounds__(256) void pool_final_logits(
    const float* __restrict__ sumP, const float* __restrict__ maxP,
    const int* __restrict__ startg, const int* __restrict__ endg,
    const float* __restrict__ Wout, const float* __restrict__ bout,
    float* __restrict__ out)
{
    __shared__ float red[256];
    __shared__ float lg[NCLS];
    int g = blockIdx.x, c = threadIdx.x;
    float s = 0.f, m = -INFINITY;
    #pragma unroll 8
    for (int part = 0; part < NPART; ++part) {
        size_t o = (size_t)(g * NPART + part) * HCDIM + c;
        s += sumP[o];
        m = fmaxf(m, maxP[o]);
    }
    int cnt = endg[g] - startg[g];
    float inv = 1.f / fmaxf((float)cnt, 1.f);
    float pv = s * inv + m;

    for (int j = 0; j < NCLS; ++j) {
        red[c] = pv * Wout[c * NCLS + j];
        __syncthreads();
        for (int off = 128; off > 0; off >>= 1) {
            if (c < off) red[c] += red[c + off];
            __syncthreads();
        }
        if (c == 0) lg[j] = red[0] + bout[j];
        __syncthreads();
    }
    if (c == 0) {
        float mx = fmaxf(lg[0], fmaxf(lg[1], lg[2]));
        float e0 = __expf(lg[0] - mx), e1 = __expf(lg[1] - mx), e2 = __expf(lg[2] - mx);
        float invs = 1.f / (e0 + e1 + e2);
        out[g * NCLS + 0] = e0 * invs;
        out[g * NCLS + 1] = e1 * invs;
        out[g * NCLS + 2] = e2 * invs;
    }
}

// ============================ Orchestration ============================
extern "C" void kernel_launch(void* const* d_in, const int* in_sizes, int n_in,
                              void* d_out, int out_size, void* d_ws, size_t ws_size,
                              hipStream_t stream) {
    const float* x     = (const float*)d_in[0];
    const int*   ei    = (const int*)d_in[1];
    const int*   batch = (const int*)d_in[2];
    const float *Wl[3], *bl[3], *Wr[3], *br[3], *att[3], *bias[3];
    for (int li = 0; li < 3; ++li) {
        int b = 3 + li * 6;
        Wl[li]   = (const float*)d_in[b + 0];
        bl[li]   = (const float*)d_in[b + 1];
        Wr[li]   = (const float*)d_in[b + 2];
        br[li]   = (const float*)d_in[b + 3];
        att[li]  = (const float*)d_in[b + 4];
        bias[li] = (const float*)d_in[b + 5];
    }
    const float* Wout = (const float*)d_in[21];
    const float* bout = (const float*)d_in[22];
    float* out = (float*)d_out;

    size_t off = 0;
    char* wsb = (char*)d_ws;
    auto alloc = [&](size_t bytes) -> char* {
        char* ptr = wsb + off;
        off += (bytes + 255) & ~(size_t)255;
        return ptr;
    };
    int* zblk    = (int*)alloc((N_NODES + 2 * NGRAPH) * sizeof(int));
    int* deg     = zblk;
    int* startg  = zblk + N_NODES;
    int* endg    = zblk + N_NODES + NGRAPH;
    int* rowptr  = (int*)alloc((N_NODES + 1) * sizeof(int));
    int* cursor  = (int*)alloc(N_NODES * sizeof(int));
    int* bsums   = (int*)alloc(256 * sizeof(int));
    int* colx    = (int*)alloc((size_t)(N_EDGES + N_NODES + COLX_PAD) * sizeof(int));
    _Float16* Abuf = (_Float16*)alloc((size_t)MPAD * HCDIM * sizeof(_Float16));
    _Float16* Bt[3];
    for (int li = 0; li < 3; ++li) {
        int K = (li == 0) ? F_INPUT : HCDIM;
        Bt[li] = (_Float16*)alloc((size_t)512 * K * sizeof(_Float16));
    }
    unsigned char* xl8 = (unsigned char*)alloc((size_t)N_NODES * HCDIM);
    _Float16* xrh  = (_Float16*)alloc((size_t)N_NODES * HCDIM * sizeof(_Float16));
    _Float16* hbuf = (_Float16*)alloc((size_t)N_NODES * HCDIM * sizeof(_Float16));
    float* sumP    = (float*)alloc((size_t)NGRAPH * NPART * HCDIM * sizeof(float));
    float* maxP    = (float*)alloc((size_t)NGRAPH * NPART * HCDIM * sizeof(float));

    hipMemsetAsync(zblk, 0, (N_NODES + 2 * NGRAPH) * sizeof(int), stream);

    hist_boundary_kernel<<<HIST_NB + BND_NB, 256, 0, stream>>>(ei, deg, batch, startg, endg);
    block_scan_kernel<<<SCAN_NB, 256, 0, stream>>>(deg, rowptr, bsums);
    add_off_kernel<<<SCAN_NB, 256, 0, stream>>>(rowptr, cursor, bsums);
    fill_kernel<<<(N_EDGES + N_NODES + COLX_PAD + 255) / 256, 256, 0, stream>>>(ei, cursor, colx);

    prep_kernel<<<PREP_NB, 256, 0, stream>>>(x, Abuf, Bt[0], Bt[1], Bt[2],
                                             Wl[0], Wr[0], Wl[1], Wr[1], Wl[2], Wr[2]);

    for (int li = 0; li < 3; ++li) {
        int K = (li == 0) ? F_INPUT : HCDIM;
        gemm_mfma<<<(MPAD / 64) * 4, 256, 0, stream>>>(
            Abuf, Bt[li], K, bl[li], br[li], xl8, xrh);
        if (li < 2) {
            gat_edge<<<N_NODES / 16, 256, 0, stream>>>(
                xl8, xrh, att[li], bias[li], rowptr, colx, nullptr, Abuf, 1);
        } else {
            gat_edge<<<N_NODES / 16, 256, 0, stream>>>(
                xl8, xrh, att[li], bias[li], rowptr, colx, hbuf, nullptr, 0);
        }
    }

    pool_partial<<<NGRAPH * NPART, 256, 0, stream>>>(hbuf, startg, endg, sumP, maxP);
    pool_final_logits<<<NGRAPH, 256, 0, stream>>>(sumP, maxP, startg, endg, Wout, bout, out);
}